// Round 8
// baseline (62.416 us; speedup 1.0000x reference)
//
#include <hip/hip_runtime.h>
#include <math.h>

constexpr int N_ITEMS = 512;
constexpr int TS      = 2048;    // TABLE_SAMPLES
constexpr int FULL    = 32768;
constexpr int PADDED  = 65536;
constexpr int NPAIR   = 512;     // BATCH * N_EVENTS
constexpr int SPLIT   = 4;       // blocks per pair
constexpr int NBLK    = NPAIR * SPLIT;   // 2048 = 8 blocks/CU * 256 CUs (exact fit)
constexpr int NPROD   = 256;     // producer blocks for items min/max

using f4 = __attribute__((ext_vector_type(4))) float;

// ---- order-preserving float <-> uint encoding ----
__device__ __forceinline__ unsigned fenc(float f) {
    unsigned u = __float_as_uint(f);
    return (u & 0x80000000u) ? ~u : (u | 0x80000000u);
}
__device__ __forceinline__ float fdec(unsigned e) {
    return __uint_as_float((e & 0x80000000u) ? (e & 0x7FFFFFFFu) : ~e);
}

// ws layout (unsigned words), memset to 0 at the start of every call:
//   ws[0] = max over producers of ~fenc(slice_min)  -> global min = fdec(~ws[0])
//   ws[1] = max over producers of  fenc(slice_max)  -> global max = fdec(ws[1])
//   ws[2] = producer completion counter (0 -> 256)
// (atomicMax identity is 0; ~fenc / fenc of real data are never 0)

__global__ void __launch_bounds__(256, 8) k_fused(const float* __restrict__ items,
                                                  const float* __restrict__ sel,
                                                  const float* __restrict__ noise,
                                                  unsigned* __restrict__ ws,
                                                  float* __restrict__ out) {
    __shared__ float row[TS];
    __shared__ unsigned sred[8];
    __shared__ int s_idx;
    __shared__ float s_w;
    __shared__ int s_fb;

    int b = blockIdx.x, t = threadIdx.x;
    int lane = t & 63, wave = t >> 6;
    int p = b >> 2, q = b & 3;

    // ---- producer phase: blocks 0..255 reduce 1/256 of the items table ----
    if (b < NPROD) {
        const f4* it4 = (const f4*)items;
        unsigned lmin = 0xFFFFFFFFu, lmax = 0u;
        #pragma unroll
        for (int k = 0; k < 4; ++k) {               // 4 f4/thread, coalesced
            f4 v = it4[(size_t)k * 65536 + b * 256 + t];
            unsigned e0 = fenc(v.x), e1 = fenc(v.y), e2 = fenc(v.z), e3 = fenc(v.w);
            lmin = min(lmin, min(min(e0, e1), min(e2, e3)));
            lmax = max(lmax, max(max(e0, e1), max(e2, e3)));
        }
        for (int off = 32; off > 0; off >>= 1) {
            lmin = min(lmin, (unsigned)__shfl_xor((int)lmin, off));
            lmax = max(lmax, (unsigned)__shfl_xor((int)lmax, off));
        }
        if (lane == 0) { sred[wave] = lmin; sred[4 + wave] = lmax; }
        __syncthreads();                             // block-uniform branch: safe
        if (t == 0) {
            unsigned bmin = min(min(sred[0], sred[1]), min(sred[2], sred[3]));
            unsigned bmax = max(max(sred[4], sred[5]), max(sred[6], sred[7]));
            atomicMax(&ws[0], ~bmin);
            atomicMax(&ws[1], bmax);
            __threadfence();
            atomicAdd(&ws[2], 1u);
        }
    }

    // ---- wave 0: this pair's sparse-softmax selection (redundant x4, L2-hot) ----
    if (wave == 0) {
        const float* s = sel + (size_t)p * N_ITEMS;
        float x[8];
        float vmax = -INFINITY;
        int   imax = 0x7FFFFFFF;
        #pragma unroll
        for (int k = 0; k < 8; ++k) {
            int i = lane + k * 64;
            x[k] = s[i];
            if (x[k] > vmax) { vmax = x[k]; imax = i; }  // ascending -> first occurrence
        }
        for (int off = 32; off > 0; off >>= 1) {
            float ov = __shfl_xor(vmax, off);
            int   oi = __shfl_xor(imax, off);
            if (ov > vmax || (ov == vmax && oi < imax)) { vmax = ov; imax = oi; }
        }
        float se = 0.0f;
        #pragma unroll
        for (int k = 0; k < 8; ++k) se += expf(x[k] - vmax);
        for (int off = 32; off > 0; off >>= 1) se += __shfl_xor(se, off);
        if (lane == 0) { s_idx = imax; s_w = 1.0f / se; }
    }

    // ---- all waves: stream this block's 32 KB pad chunk (overlaps the above) ----
    {
        constexpr int PCHUNK = (PADDED - FULL) / SPLIT;  // 8192 floats
        f4* pad4 = (f4*)(out + (size_t)p * PADDED + FULL + (size_t)q * PCHUNK);
        f4 z = {0.f, 0.f, 0.f, 0.f};
        #pragma unroll
        for (int k = 0; k < 8; ++k)
            __builtin_nontemporal_store(z, &pad4[t + k * 256]);
    }

    __syncthreads();                     // s_idx / s_w visible
    int   idx = s_idx;
    float w   = s_w;

    // ---- issue row loads + 8-deep noise prefetch; stage RAW row in LDS ----
    const f4* it4 = (const f4*)(items + (size_t)idx * TS);
    f4 r0 = it4[t];
    f4 r1 = it4[t + 256];

    const f4* nz4 = (const f4*)(noise + (size_t)p * FULL + (size_t)q * (FULL / SPLIT));
    f4 nzv[8];
    #pragma unroll
    for (int k = 0; k < 8; ++k)
        nzv[k] = nz4[t + k * 256];

    ((f4*)row)[t]       = r0;            // raw row; affine applied after lerp
    ((f4*)row)[t + 256] = r1;

    // ---- wait for producers (thread 0 decides; timeout -> self-compute) ----
    if (t == 0) {
        int fb = 0;
        long long start = clock64();
        while (__hip_atomic_load(&ws[2], __ATOMIC_ACQUIRE, __HIP_MEMORY_SCOPE_AGENT) < NPROD) {
            __builtin_amdgcn_s_sleep(8);
            if (clock64() - start > 10000000LL) { fb = 1; break; }
        }
        s_fb = fb;
    }
    __syncthreads();                     // row staged + s_fb visible

    float minv, maxv;
    if (s_fb) {
        // fallback (dispatch-order pathology only): full-table scan, block-local
        const f4* a4 = (const f4*)items;
        unsigned lmin = 0xFFFFFFFFu, lmax = 0u;
        for (int i = t; i < (N_ITEMS * TS) / 4; i += 256) {
            f4 v = a4[i];
            unsigned e0 = fenc(v.x), e1 = fenc(v.y), e2 = fenc(v.z), e3 = fenc(v.w);
            lmin = min(lmin, min(min(e0, e1), min(e2, e3)));
            lmax = max(lmax, max(max(e0, e1), max(e2, e3)));
        }
        for (int off = 32; off > 0; off >>= 1) {
            lmin = min(lmin, (unsigned)__shfl_xor((int)lmin, off));
            lmax = max(lmax, (unsigned)__shfl_xor((int)lmax, off));
        }
        if (lane == 0) { sred[wave] = lmin; sred[4 + wave] = lmax; }
        __syncthreads();                 // block-uniform branch: safe
        unsigned bmin = min(min(sred[0], sred[1]), min(sred[2], sred[3]));
        unsigned bmax = max(max(sred[4], sred[5]), max(sred[6], sred[7]));
        minv = fdec(bmin);
        maxv = fdec(bmax);
    } else {
        unsigned im = __hip_atomic_load(&ws[0], __ATOMIC_RELAXED, __HIP_MEMORY_SCOPE_AGENT);
        unsigned mx = __hip_atomic_load(&ws[1], __ATOMIC_RELAXED, __HIP_MEMORY_SCOPE_AGENT);
        minv = fdec(~im);
        maxv = fdec(mx);
    }
    float denom = (maxv - minv) + 0.001f;
    float scale = w / denom;
    float bias  = -minv * scale;

    // ---- stream: lerp raw row, apply affine, multiply noise, store amp ----
    f4* o4 = (f4*)(out + (size_t)p * PADDED + (size_t)q * (FULL / SPLIT));
    int tbase = q * (FULL / SPLIT);

    #pragma unroll
    for (int k = 0; k < 8; ++k) {
        int v  = t + k * 256;
        int t0 = tbase + v * 4;
        float pos0 = ((float)t0 + 0.5f) * 0.0625f - 0.5f;   // in/out = 1/16 exact
        f4 o;
        #pragma unroll
        for (int j = 0; j < 4; ++j) {
            float pj = fminf(fmaxf(pos0 + (float)j * 0.0625f, 0.0f), (float)(TS - 1));
            int   lj = (int)pj;                  // trunc == floor (>=0)
            int   hj = min(lj + 1, TS - 1);
            float fr = pj - (float)lj;
            float raw = row[lj] * (1.0f - fr) + row[hj] * fr;
            o[j] = fmaf(raw, scale, bias) * nzv[k][j];
        }
        __builtin_nontemporal_store(o, &o4[v]);
    }
}

extern "C" void kernel_launch(void* const* d_in, const int* in_sizes, int n_in,
                              void* d_out, int out_size, void* d_ws, size_t ws_size,
                              hipStream_t stream) {
    const float* sel   = (const float*)d_in[0];   // [8,64,512]
    const float* items = (const float*)d_in[1];   // [512,2048]
    const float* noise = (const float*)d_in[2];   // [8,64,32768]
    float* out = (float*)d_out;                   // [8,64,65536]
    unsigned* ws = (unsigned*)d_ws;

    hipMemsetAsync(ws, 0, 16, stream);            // atomics + counter identity
    hipLaunchKernelGGL(k_fused, dim3(NBLK), dim3(256), 0, stream,
                       items, sel, noise, ws, out);
}

// Round 9
// 40.096 us; speedup vs baseline: 1.5567x; 1.5567x over previous
//
#include <hip/hip_runtime.h>
#include <math.h>

constexpr int N_ITEMS = 512;
constexpr int TS      = 2048;    // TABLE_SAMPLES
constexpr int FULL    = 32768;
constexpr int PADDED  = 65536;
constexpr int NPAIR   = 512;     // BATCH * N_EVENTS
constexpr int SPLIT   = 4;       // main: blocks per pair
constexpr int NMM     = 64;      // min/max partial blocks

using f4 = __attribute__((ext_vector_type(4))) float;

// ---- order-preserving float <-> uint encoding for min/max over partials ----
__device__ __forceinline__ unsigned fenc(float f) {
    unsigned u = __float_as_uint(f);
    return (u & 0x80000000u) ? ~u : (u | 0x80000000u);
}
__device__ __forceinline__ float fdec(unsigned e) {
    return __uint_as_float((e & 0x80000000u) ? (e & 0x7FFFFFFFu) : ~e);
}

// ws layout (bytes):
//   [0    ..  255]  min partials, unsigned[64]
//   [256  ..  511]  max partials, unsigned[64]
//   [512  .. 2559]  idx, int[512]
//   [2560 .. 4607]  w,   float[512]

// k_prep, grid = 192 x 256 — reductions only (~5 MB, ~3 us):
//   blocks 0..63  : min/max partials over 1/64 of the items table
//   blocks 64..191: sparse-softmax selection, 4 pairs per block (1 wave each)
__global__ void __launch_bounds__(256) k_prep(const f4* __restrict__ items4,
                                              const float* __restrict__ sel,
                                              unsigned* __restrict__ ws_min,
                                              unsigned* __restrict__ ws_max,
                                              int* __restrict__ ws_idx,
                                              float* __restrict__ ws_w) {
    __shared__ unsigned smin[4], smax[4];
    int blk = blockIdx.x;
    int tid = threadIdx.x;

    if (blk < NMM) {
        unsigned lmin = 0xFFFFFFFFu, lmax = 0u;
        const int NV = (N_ITEMS * TS) / 4;              // 262144 float4
        for (int i = blk * 256 + tid; i < NV; i += NMM * 256) {   // 16 iters
            f4 v = items4[i];
            unsigned e0 = fenc(v.x), e1 = fenc(v.y), e2 = fenc(v.z), e3 = fenc(v.w);
            lmin = min(min(min(lmin, e0), min(e1, e2)), e3);
            lmax = max(max(max(lmax, e0), max(e1, e2)), e3);
        }
        for (int off = 32; off > 0; off >>= 1) {
            lmin = min(lmin, (unsigned)__shfl_xor((int)lmin, off));
            lmax = max(lmax, (unsigned)__shfl_xor((int)lmax, off));
        }
        int wave = tid >> 6;
        if ((tid & 63) == 0) { smin[wave] = lmin; smax[wave] = lmax; }
        __syncthreads();
        if (tid == 0) {
            ws_min[blk] = min(min(smin[0], smin[1]), min(smin[2], smin[3]));
            ws_max[blk] = max(max(smax[0], smax[1]), max(smax[2], smax[3]));
        }
    } else {
        int p    = (blk - NMM) * 4 + (tid >> 6);
        int lane = tid & 63;
        const float* s = sel + (size_t)p * N_ITEMS;
        float x[8];
        float vmax = -INFINITY;
        int   imax = 0x7FFFFFFF;
        #pragma unroll
        for (int k = 0; k < 8; ++k) {
            int i = lane + k * 64;
            x[k] = s[i];
            if (x[k] > vmax) { vmax = x[k]; imax = i; }  // ascending -> first occurrence
        }
        for (int off = 32; off > 0; off >>= 1) {
            float ov = __shfl_xor(vmax, off);
            int   oi = __shfl_xor(imax, off);
            if (ov > vmax || (ov == vmax && oi < imax)) { vmax = ov; imax = oi; }
        }
        float se = 0.0f;
        #pragma unroll
        for (int k = 0; k < 8; ++k) se += expf(x[k] - vmax);
        for (int off = 32; off > 0; off >>= 1) se += __shfl_xor(se, off);
        if (lane == 0) { ws_idx[p] = imax; ws_w[p] = 1.0f / se; }
    }
}

// k_main, grid = 2048 x 256: block = (pair, quarter). Carries all 201 MB.
// Minimal prologue: 6-shuffle wave reduce of 64 partials, 2 KB raw slice
// staged in LDS (affine folded in after the lerp), 8-deep noise prefetch
// issued first. Plain loads/stores throughout.
__global__ void __launch_bounds__(256, 8) k_main(const float* __restrict__ items,
                                                 const float* __restrict__ noise,
                                                 const unsigned* __restrict__ ws_min,
                                                 const unsigned* __restrict__ ws_max,
                                                 const int* __restrict__ ws_idx,
                                                 const float* __restrict__ ws_w,
                                                 float* __restrict__ out) {
    __shared__ float slice[520];     // raw samples [sbase-1 .. sbase+518] clamped

    int blk  = blockIdx.x;
    int p    = blk >> 2;             // SPLIT = 4
    int q    = blk & 3;
    int tid  = threadIdx.x;
    int lane = tid & 63;

    // wave-local reduce of the 64 min/max partials (1 load + 6 shuffles each)
    unsigned gmin = ws_min[lane], gmax = ws_max[lane];
    for (int off = 32; off > 0; off >>= 1) {
        gmin = min(gmin, (unsigned)__shfl_xor((int)gmin, off));
        gmax = max(gmax, (unsigned)__shfl_xor((int)gmax, off));
    }
    float minv  = fdec(gmin);
    float maxv  = fdec(gmax);
    float denom = (maxv - minv) + 0.001f;
    int   idx   = ws_idx[p];
    float scale = ws_w[p] / denom;
    float bias  = -minv * scale;

    constexpr int CHUNK = FULL / SPLIT;              // 8192 floats (amp)
    const f4* nz4  = (const f4*)(noise + (size_t)p * FULL + (size_t)q * CHUNK);
    f4*       o4   = (f4*)(out + (size_t)p * PADDED + (size_t)q * CHUNK);
    f4*       pad4 = (f4*)(out + (size_t)p * PADDED + FULL + (size_t)q * CHUNK);
    int tbase = q * CHUNK;
    int sbase = q * (CHUNK / 16);                    // 512 samples per quarter

    // 8-deep noise prefetch (keeps the read stream full through the barrier)
    f4 nzv[8];
    #pragma unroll
    for (int k = 0; k < 8; ++k)
        nzv[k] = nz4[tid + k * 256];

    // stage the raw 520-float slice (L2-hot row segment, ~2 KB)
    const float* grow = items + (size_t)idx * TS;
    #pragma unroll
    for (int s = tid; s < 520; s += 256)
        slice[s] = grow[min(max(sbase - 1 + s, 0), TS - 1)];
    __syncthreads();

    // pad-zero stream (independent of everything; fills the store pipe)
    f4 z = {0.f, 0.f, 0.f, 0.f};
    #pragma unroll
    for (int k = 0; k < 8; ++k)
        pad4[tid + k * 256] = z;

    // amp stream: lerp raw slice, apply affine, multiply noise
    #pragma unroll
    for (int k = 0; k < 8; ++k) {
        int v  = tid + k * 256;
        int t0 = tbase + v * 4;
        float pos0 = ((float)t0 + 0.5f) * 0.0625f - 0.5f;   // in/out = 1/16 exact
        f4 o;
        #pragma unroll
        for (int j = 0; j < 4; ++j) {
            float pj = fminf(fmaxf(pos0 + (float)j * 0.0625f, 0.0f), (float)(TS - 1));
            int   lj = (int)pj;                  // trunc == floor (>=0)
            float fr = pj - (float)lj;
            int   loc = lj - sbase + 1;          // slice-local, in [0, 513]
            float a = slice[loc];
            float bsm = slice[loc + 1];          // hj=min(lj+1,2047) handled by clamp-staging
            float raw = fmaf(fr, bsm - a, a);
            o[j] = fmaf(raw, scale, bias) * nzv[k][j];
        }
        o4[v] = o;
    }
}

extern "C" void kernel_launch(void* const* d_in, const int* in_sizes, int n_in,
                              void* d_out, int out_size, void* d_ws, size_t ws_size,
                              hipStream_t stream) {
    const float* sel   = (const float*)d_in[0];   // [8,64,512]
    const float* items = (const float*)d_in[1];   // [512,2048]
    const float* noise = (const float*)d_in[2];   // [8,64,32768]
    float* out = (float*)d_out;                   // [8,64,65536]

    unsigned* ws_min = (unsigned*)d_ws;
    unsigned* ws_max = (unsigned*)((char*)d_ws + 256);
    int*      ws_idx = (int*)((char*)d_ws + 512);
    float*    ws_w   = (float*)((char*)d_ws + 2560);

    hipLaunchKernelGGL(k_prep, dim3(NMM + NPAIR / 4), dim3(256), 0, stream,
                       (const f4*)items, sel, ws_min, ws_max, ws_idx, ws_w);
    hipLaunchKernelGGL(k_main, dim3(NPAIR * SPLIT), dim3(256), 0, stream,
                       items, noise, ws_min, ws_max, ws_idx, ws_w, out);
}